// Round 4
// baseline (6250.241 us; speedup 1.0000x reference)
//
#include <hip/hip_runtime.h>

// LSTM_3813930958978: T=512, B=64, I=1024, H=1024, gate order i,f,g,o.
//
// R1: h-path via global_load_lds DMA (SC0|SC1), fences removed. 8490->4845.
// R2: x-path DMA staged. 4845->3290.
// R3: xg = x@W_ih^T hoisted to a pre-pass. persist 2400us (4.69us/step),
//     xg_gemm ~980us. Both phases ~equally slow per iteration despite
//     xg_gemm having NO global sync -> shared bottleneck: XCD<->MALL link
//     BW (persist: 16 blk x 128KB sc1-bypass h per XCD per step; xg: 2
//     drifting t-streams x 32 blk x 128KB x reads).
// R4 (this round):
//  - persist h reads L2-CACHED (aux=0) + per-wave acquire fence
//    (buffer_inv) after the poll (R0-proven coherence pattern): 16
//    same-XCD blocks share one h fetch -> ~16x less MALL link traffic.
//  - 2-level arrival tree + epoch -> 128-word flag array (4 lines):
//    arrival = 1 relaxed agent store; all waves poll 2 flags/lane.
//    Saves ~2 MALL RMW round-trips per step.
//  - h staging 3 chunks up-front (3-buf): one exposed MALL latency/step.
//    xg register loads issued AFTER the fence (fence's vmcnt(0) would
//    otherwise stall on them).
//  - xg_gemm: blocks = (cb, row-half); same-XCD blocks read the SAME
//    64KB x row-half at the SAME t -> real L2 sharing. 3-buf staging;
//    xg stores issued after prefetch so vmcnt waits don't drain them.

#define TT 512
#define BB 64
#define II 1024
#define HHH 1024
#define G4 4096
#define NBLK 128
#define HPB 8

typedef __attribute__((ext_vector_type(8))) short short8;
typedef __attribute__((ext_vector_type(4))) float f32x4;
typedef __attribute__((ext_vector_type(4))) int i32x4;

typedef __attribute__((address_space(1))) const void gvoid;
typedef __attribute__((address_space(3))) void lvoid;

__device__ __forceinline__ short8 load_frag(const unsigned short* p) {
  i32x4 v = *(const i32x4*)p;
  return __builtin_bit_cast(short8, v);
}

__device__ __forceinline__ unsigned short f2bf(float f) {
  unsigned u = __builtin_bit_cast(unsigned, f);
  u = (u + 0x7FFFu + ((u >> 16) & 1u)) >> 16;
  return (unsigned short)u;
}

__device__ __forceinline__ float sigm(float x) {
  return 1.0f / (1.0f + __expf(-x));
}
__device__ __forceinline__ float tanh_f(float x) {
  return 2.0f / (1.0f + __expf(-2.0f * x)) - 1.0f;
}

// ---- conversion kernels ------------------------------------------------
__global__ void cvt_bf16(const float* __restrict__ s,
                         unsigned short* __restrict__ d, int n4) {
  int stride = gridDim.x * blockDim.x;
  for (int i = blockIdx.x * blockDim.x + threadIdx.x; i < n4; i += stride) {
    f32x4 v = *(const f32x4*)(s + 4 * i);
    unsigned lo = (unsigned)f2bf(v[0]) | ((unsigned)f2bf(v[1]) << 16);
    unsigned hi = (unsigned)f2bf(v[2]) | ((unsigned)f2bf(v[3]) << 16);
    uint2 u; u.x = lo; u.y = hi;
    *(uint2*)(d + 4 * i) = u;
  }
}

__global__ void bias_sum(const float* __restrict__ a,
                         const float* __restrict__ b,
                         float* __restrict__ o) {
  int i = blockIdx.x * blockDim.x + threadIdx.x;
  if (i < G4) o[i] = a[i] + b[i];
}

// ---- xg precompute: xg[cb][t][64][32] = x_t @ W_ih^T + bias -----------
// 256 blocks = 128 cb x 2 row-halves. Block (cb,mh) computes rows
// mh*32..+32 for ALL t. Same-XCD blocks (bid%8 fixed) share mh parity ->
// identical 64KB x row-half working set at the same t -> L2-shared.
__global__ __launch_bounds__(256, 1) void xg_gemm(
    const unsigned short* __restrict__ xb,    // [T][64][1024] bf16
    const unsigned short* __restrict__ wih,   // [4096][1024] bf16
    const float* __restrict__ bsum,           // [4096] f32
    char* __restrict__ xg, int xg32)
{
  const int tid = threadIdx.x;
  const int wid = tid >> 6;
  const int lane = tid & 63;
  const int ln15 = lane & 15;
  const int quad = lane >> 4;
  const int cb = blockIdx.x >> 1;
  const int mh = blockIdx.x & 1;
  const int hc0 = cb * HPB;
  const int koff = wid * 256;                 // 4-way K split

  __shared__ float red[4][32][36];
  __shared__ __align__(16) short xstage[4][3][4096];  // [wave][buf][8KB]

  // persistent W_ih B-fragments: per wave K=256 -> bfrag[8][2]
  short8 bfrag[8][2];
#pragma unroll
  for (int nt = 0; nt < 2; ++nt) {
    int n = nt * 16 + ln15;
    int grow = (n >> 3) * 1024 + hc0 + (n & 7);
#pragma unroll
    for (int kc = 0; kc < 8; ++kc) {
      int k = koff + kc * 32 + quad * 8;
      bfrag[kc][nt] = load_frag(wih + grow * 1024 + k);
    }
  }

  const int eb = tid >> 3;   // 0..31: row within half
  const int er = tid & 7;    // h-col within block
  float bsv[4];
#pragma unroll
  for (int q = 0; q < 4; ++q) bsv[q] = bsum[q * 1024 + hc0 + er];

  // staging: chunk ck = rows [mh*32+ck*16, +16), cols koff..koff+256.
  // instr j moves rows 2j,2j+1 (1KB): lane>>5 = row parity, lane&31 = col.
  const unsigned xsl = (unsigned)(lane >> 5) * 2048u +
                       (unsigned)(lane & 31) * 16u;
  const size_t wbase = (size_t)(mh * 32) * 2048u + (unsigned)wid * 512u;

  f32x4 acc[2][2];

  auto stage_x = [&](int t, int ck, int buf) {
    short* lb = &xstage[wid][buf][0];
    const char* gt = (const char*)xb + (size_t)t * 131072u + wbase +
                     (unsigned)ck * 32768u + xsl;
#pragma unroll
    for (int j = 0; j < 8; ++j) {
      __builtin_amdgcn_global_load_lds((gvoid*)(gt + j * 4096),
                                       (lvoid*)(lb + j * 512), 16, 0, 0);
    }
  };
  auto comp_x = [&](int m, int buf) {
    const char* lb = (const char*)&xstage[wid][buf][0];
#pragma unroll
    for (int kc = 0; kc < 8; ++kc) {
      unsigned loff = (unsigned)ln15 * 512u + (unsigned)kc * 64u +
                      (unsigned)quad * 16u;
      short8 a = *(const short8*)(lb + loff);
      acc[m][0] = __builtin_amdgcn_mfma_f32_16x16x32_bf16(
          a, bfrag[kc][0], acc[m][0], 0, 0, 0);
      acc[m][1] = __builtin_amdgcn_mfma_f32_16x16x32_bf16(
          a, bfrag[kc][1], acc[m][1], 0, 0, 0);
    }
  };

  stage_x(0, 0, 0);
  stage_x(0, 1, 1);
  int b0 = 0, b1 = 1, b2 = 2;

#pragma unroll 1
  for (int t = 0; t < TT; ++t) {
#pragma unroll
    for (int m = 0; m < 2; ++m)
#pragma unroll
      for (int nt = 0; nt < 2; ++nt)
        acc[m][nt] = (f32x4){0.0f, 0.0f, 0.0f, 0.0f};

    asm volatile("s_waitcnt vmcnt(8)" ::: "memory");   // ck0 landed
    comp_x(0, b0);
    asm volatile("s_waitcnt lgkmcnt(0)" ::: "memory");
    if (t < TT - 1) stage_x(t + 1, 0, b2);
    asm volatile("s_waitcnt vmcnt(8)" ::: "memory");   // ck1 landed
    comp_x(1, b1);
    asm volatile("s_waitcnt lgkmcnt(0)" ::: "memory");
    if (t < TT - 1) stage_x(t + 1, 1, b0);
    int nb0 = b2, nb1 = b0, nb2 = b1;
    b0 = nb0; b1 = nb1; b2 = nb2;

    // dump partials (rows 0..31 within half)
#pragma unroll
    for (int m = 0; m < 2; ++m)
#pragma unroll
      for (int nt = 0; nt < 2; ++nt)
#pragma unroll
        for (int p = 0; p < 4; ++p)
          red[wid][m * 16 + quad * 4 + p][nt * 16 + ln15] = acc[m][nt][p];

    asm volatile("s_waitcnt lgkmcnt(0)" ::: "memory");
    __builtin_amdgcn_s_barrier();

    // reduce + bias, write xg (stores sit BEHIND the prefetch in vmcnt)
    float g[4];
#pragma unroll
    for (int q = 0; q < 4; ++q) {
      int col = q * 8 + er;
      g[q] = red[0][eb][col] + red[1][eb][col] + red[2][eb][col] +
             red[3][eb][col] + bsv[q];
    }
    size_t xoff = (((size_t)cb * 512 + (size_t)t) * 64 +
                   (size_t)(mh * 32 + eb)) * 32 + (size_t)er;
    if (xg32) {
      float* xp = (float*)xg + xoff;
#pragma unroll
      for (int q = 0; q < 4; ++q) xp[q * 8] = g[q];
    } else {
      unsigned short* xp = (unsigned short*)xg + xoff;
#pragma unroll
      for (int q = 0; q < 4; ++q) xp[q * 8] = f2bf(g[q]);
    }

    __builtin_amdgcn_s_barrier();   // raw: no vmcnt drain
  }
}

// ---- persistent LSTM recurrence ---------------------------------------
// h layout: [2][128 cb][64 row][8 col] bf16. Wave w reads one contiguous
// 32KB span (L2-cached, XCD-shared); block stores one 1KB slice (sc0sc1).
// flags[cb] (128 words, 4 cachelines): block cb sets flags[cb]=t+1 after
// its h(t+1) is drained; all waves poll 2 flags/lane, then acquire-fence.
__global__ __launch_bounds__(256, 1) void lstm_persist(
    const unsigned short* __restrict__ whh,   // [4096][1024] bf16
    const char* __restrict__ xg, int xg32,    // [128][512][64][32]
    unsigned short* __restrict__ hbuf,        // 2 x [128][64][8] bf16
    unsigned int* __restrict__ flags,         // zeroed
    float* __restrict__ out)                  // [64][1024] f32
{
  const int tid = threadIdx.x;
  const int wid = tid >> 6;
  const int lane = tid & 63;
  const int ln15 = lane & 15;
  const int quad = lane >> 4;
  const int cb = blockIdx.x;
  const int hc0 = cb * HPB;
  const int koff = wid * 256;        // 4-way K split over W_hh

  __shared__ float red[4][64][36];
  __shared__ __align__(16) short hstage[4][3][4096];  // [wave][buf][8KB]

  // persistent W_hh B-fragments
  short8 bfrag[8][2];
#pragma unroll
  for (int nt = 0; nt < 2; ++nt) {
    int n = nt * 16 + ln15;
    int grow = (n >> 3) * 1024 + hc0 + (n & 7);
#pragma unroll
    for (int kc = 0; kc < 8; ++kc) {
      int k = koff + kc * 32 + quad * 8;
      bfrag[kc][nt] = load_frag(whh + grow * 1024 + k);
    }
  }

  const int eb = tid >> 2;
  const int erp = tid & 3;
  const size_t xbase0 = (((size_t)cb * 512) * 64 + (size_t)eb) * 32 +
                        (size_t)(erp * 2);

  float cst[2] = {0.0f, 0.0f};
  f32x4 acc[4][2];
  float xgv[4][2];

  auto load_xg = [&](int t) {
    if (xg32) {
      const float* xp = (const float*)xg + xbase0 + (size_t)t * 2048u;
#pragma unroll
      for (int q = 0; q < 4; ++q) {
        float2 v = *(const float2*)(xp + q * 8);
        xgv[q][0] = v.x; xgv[q][1] = v.y;
      }
    } else {
      const unsigned short* xp =
          (const unsigned short*)xg + xbase0 + (size_t)t * 2048u;
#pragma unroll
      for (int q = 0; q < 4; ++q) {
        unsigned u = *(const unsigned*)(xp + q * 8);
        xgv[q][0] = __builtin_bit_cast(float, u << 16);
        xgv[q][1] = __builtin_bit_cast(float, u & 0xffff0000u);
      }
    }
  };

  auto stage = [&](const char* gsrc, int ck, int buf) {
    short* lb = &hstage[wid][buf][0];
    const char* gs = gsrc + wid * 32768 + ck * 8192 + (unsigned)lane * 16u;
#pragma unroll
    for (int j = 0; j < 8; ++j) {
      __builtin_amdgcn_global_load_lds((gvoid*)(gs + j * 1024),
                                       (lvoid*)(lb + j * 512),
                                       16, 0, 0);  // CACHED: L2 XCD-shared
    }
  };
  auto comp = [&](int ck, int buf) {
    const char* lb = (const char*)&hstage[wid][buf][0];
#pragma unroll
    for (int kl = 0; kl < 2; ++kl) {
      int kc = ck * 2 + kl;
#pragma unroll
      for (int m = 0; m < 4; ++m) {
        unsigned loff = (unsigned)(kl * 4 + quad) * 1024u +
                        (unsigned)(m * 16 + ln15) * 16u;
        short8 a = *(const short8*)(lb + loff);
        acc[m][0] = __builtin_amdgcn_mfma_f32_16x16x32_bf16(
            a, bfrag[kc][0], acc[m][0], 0, 0, 0);
        acc[m][1] = __builtin_amdgcn_mfma_f32_16x16x32_bf16(
            a, bfrag[kc][1], acc[m][1], 0, 0, 0);
      }
    }
  };

#pragma unroll 1
  for (int t = 0; t < TT; ++t) {
#pragma unroll
    for (int m = 0; m < 4; ++m)
#pragma unroll
      for (int nt = 0; nt < 2; ++nt)
        acc[m][nt] = (f32x4){0.0f, 0.0f, 0.0f, 0.0f};

    if (t) {
      // all waves poll: lane l watches flags[l] and flags[64+l]
      for (;;) {
        unsigned f0 = __hip_atomic_load(flags + lane, __ATOMIC_RELAXED,
                                        __HIP_MEMORY_SCOPE_AGENT);
        unsigned f1 = __hip_atomic_load(flags + 64 + lane, __ATOMIC_RELAXED,
                                        __HIP_MEMORY_SCOPE_AGENT);
        if (__all((f0 >= (unsigned)t) && (f1 >= (unsigned)t))) break;
        __builtin_amdgcn_s_sleep(1);
      }
      // acquire: invalidate L1/L2 so cached h loads see MALL-fresh data
      __builtin_amdgcn_fence(__ATOMIC_ACQUIRE, "agent");

      load_xg(t);   // after fence: its latency hides under h DMA waits

      const char* gsrc = (const char*)(hbuf + (t & 1) * 65536);
      stage(gsrc, 0, 0);
      stage(gsrc, 1, 1);
      stage(gsrc, 2, 2);
      asm volatile("s_waitcnt vmcnt(16)" ::: "memory");  // c0 landed
      comp(0, 0);
      asm volatile("s_waitcnt lgkmcnt(0)" ::: "memory"); // b0 reads done
      stage(gsrc, 3, 0);
      asm volatile("s_waitcnt vmcnt(16)" ::: "memory");  // c1 landed
      comp(1, 1);
      asm volatile("s_waitcnt vmcnt(8)" ::: "memory");   // c2 landed
      comp(2, 2);
      asm volatile("s_waitcnt vmcnt(0)" ::: "memory");   // c3 landed
      comp(3, 0);
    } else {
      load_xg(t);
    }
    // t==0: h0 = 0 -> gates are xg only; acc stays zero.

#pragma unroll
    for (int m = 0; m < 4; ++m)
#pragma unroll
      for (int nt = 0; nt < 2; ++nt)
#pragma unroll
        for (int p = 0; p < 4; ++p)
          red[wid][m * 16 + quad * 4 + p][nt * 16 + ln15] = acc[m][nt][p];

    asm volatile("s_waitcnt lgkmcnt(0)" ::: "memory");
    __builtin_amdgcn_s_barrier();   // (#1) raw

    float hv[2];
#pragma unroll
    for (int rr = 0; rr < 2; ++rr) {
      int r = erp * 2 + rr;
      float g[4];
#pragma unroll
      for (int q = 0; q < 4; ++q) {
        int col = q * 8 + r;
        g[q] = red[0][eb][col] + red[1][eb][col] + red[2][eb][col] +
               red[3][eb][col] + xgv[q][rr];
      }
      float ig = sigm(g[0]);
      float fg = sigm(g[1]);
      float gg = tanh_f(g[2]);
      float og = sigm(g[3]);
      float c = fg * cst[rr] + ig * gg;
      cst[rr] = c;
      hv[rr] = og * tanh_f(c);
    }
    unsigned hpack = (unsigned)f2bf(hv[0]) | ((unsigned)f2bf(hv[1]) << 16);
    // agent-scope write-through: lands at MALL; syncthreads drains it
    __hip_atomic_store(
        (unsigned*)(hbuf + ((t + 1) & 1) * 65536 + cb * 512 + eb * 8 +
                    erp * 2),
        hpack, __ATOMIC_RELAXED, __HIP_MEMORY_SCOPE_AGENT);

    if (t == TT - 1) {
      float2 o2; o2.x = hv[0]; o2.y = hv[1];
      *(float2*)(out + eb * HHH + hc0 + erp * 2) = o2;
    }

    __syncthreads();   // (#2) vmcnt(0): all h stores MALL-visible

    if (t < TT - 1 && tid == 0)
      __hip_atomic_store(flags + cb, (unsigned)(t + 1), __ATOMIC_RELAXED,
                         __HIP_MEMORY_SCOPE_AGENT);
  }
}

// ---- launcher ----------------------------------------------------------
extern "C" void kernel_launch(void* const* d_in, const int* in_sizes, int n_in,
                              void* d_out, int out_size, void* d_ws,
                              size_t ws_size, hipStream_t stream) {
  (void)in_sizes; (void)n_in; (void)out_size;
  const float* x   = (const float*)d_in[0];
  const float* wih = (const float*)d_in[1];
  const float* whh = (const float*)d_in[2];
  const float* bih = (const float*)d_in[3];
  const float* bhh = (const float*)d_in[4];

  char* ws = (char*)d_ws;
  // workspace layout (bytes):
  //   [0, 4096)          flags (128 words) + padding
  //   [4096, +256KiB)    h double buffer (2 x 128x64x8 bf16, blocked)
  //   [1MiB, 9MiB)       W_ih bf16
  //   [9MiB, 17MiB)      W_hh bf16
  //   [17MiB, +16KiB)    bias sum f32
  //   [18MiB, 82MiB)     x bf16
  //   [96MiB, ...)       xg: f32 512MiB if ws fits, else bf16 256MiB
  unsigned int*   flg  = (unsigned int*)(ws);
  unsigned short* hb   = (unsigned short*)(ws + 4096);
  unsigned short* wihb = (unsigned short*)(ws + (1ull << 20));
  unsigned short* whhb = (unsigned short*)(ws + (9ull << 20));
  float*          bs   = (float*)(ws + (17ull << 20));
  unsigned short* xb   = (unsigned short*)(ws + (18ull << 20));
  char*           xg   = ws + (96ull << 20);
  int xg32 = (ws_size >= (640ull << 20)) ? 1 : 0;

  hipMemsetAsync(ws, 0, 4096, stream);

  cvt_bf16<<<2048, 256, 0, stream>>>(x, xb, (TT * BB * II) / 4);
  cvt_bf16<<<1024, 256, 0, stream>>>(wih, wihb, (G4 * II) / 4);
  cvt_bf16<<<1024, 256, 0, stream>>>(whh, whhb, (G4 * HHH) / 4);
  bias_sum<<<16, 256, 0, stream>>>(bih, bhh, bs);

  xg_gemm<<<256, 256, 0, stream>>>(xb, wihb, bs, xg, xg32);
  lstm_persist<<<NBLK, 256, 0, stream>>>(whhb, xg, xg32, hb, flg,
                                         (float*)d_out);
}

// Round 6
// 3400.223 us; speedup vs baseline: 1.8382x; 1.8382x over previous
//
#include <hip/hip_runtime.h>

// LSTM_3813930958978: T=512, B=64, I=1024, H=1024, gate order i,f,g,o.
//
// R1: h DMA via global_load_lds (SC0|SC1). 8490->4845.
// R2: x DMA staged. 4845->3290.
// R3: xg=x@W_ih^T hoisted; persist 2400us + xg_gemm ~1050us = 3483.
// R4: cached h + PER-STEP acquire fence = regression (5014us): buffer_inv
//     wiped L2 every step.
// R5: fused producer/consumer (256 blocks) hung the container twice --
//     needs all-256-CU co-residency, which is not guaranteed. Reverted.
// R6 (this round): R3 structure + write-once h slabs:
//  - h lives in a 64-slab history ring (8MB). A slab address is re-
//    written only 63 steps after its last read, so L2-CACHED (aux=0)
//    h reads are safe with an agent acquire-fence every 32 steps
//    (>=1 inv between any read and that address's re-read). 16 same-XCD
//    consumers now share ONE 128KB MALL fetch per step instead of 16.
//  - everything else (tree/epoch barrier, staging schedule, xg_gemm)
//    is R3-verbatim for attribution.

#define TT 512
#define BB 64
#define II 1024
#define HHH 1024
#define G4 4096
#define NBLK 128
#define HPB 8

typedef __attribute__((ext_vector_type(8))) short short8;
typedef __attribute__((ext_vector_type(4))) float f32x4;
typedef __attribute__((ext_vector_type(4))) int i32x4;

typedef __attribute__((address_space(1))) const void gvoid;
typedef __attribute__((address_space(3))) void lvoid;

__device__ __forceinline__ short8 load_frag(const unsigned short* p) {
  i32x4 v = *(const i32x4*)p;
  return __builtin_bit_cast(short8, v);
}

__device__ __forceinline__ unsigned short f2bf(float f) {
  unsigned u = __builtin_bit_cast(unsigned, f);
  u = (u + 0x7FFFu + ((u >> 16) & 1u)) >> 16;
  return (unsigned short)u;
}

__device__ __forceinline__ float sigm(float x) {
  return 1.0f / (1.0f + __expf(-x));
}
__device__ __forceinline__ float tanh_f(float x) {
  return 2.0f / (1.0f + __expf(-2.0f * x)) - 1.0f;
}

// ---- conversion kernels ------------------------------------------------
__global__ void cvt_bf16(const float* __restrict__ s,
                         unsigned short* __restrict__ d, int n4) {
  int stride = gridDim.x * blockDim.x;
  for (int i = blockIdx.x * blockDim.x + threadIdx.x; i < n4; i += stride) {
    f32x4 v = *(const f32x4*)(s + 4 * i);
    unsigned lo = (unsigned)f2bf(v[0]) | ((unsigned)f2bf(v[1]) << 16);
    unsigned hi = (unsigned)f2bf(v[2]) | ((unsigned)f2bf(v[3]) << 16);
    uint2 u; u.x = lo; u.y = hi;
    *(uint2*)(d + 4 * i) = u;
  }
}

__global__ void bias_sum(const float* __restrict__ a,
                         const float* __restrict__ b,
                         float* __restrict__ o) {
  int i = blockIdx.x * blockDim.x + threadIdx.x;
  if (i < G4) o[i] = a[i] + b[i];
}

// ---- xg precompute: xg[cb][t][64][32] = x_t @ W_ih^T + bias -----------
// (R3 verbatim.) 256 blocks x 256 threads, 1 block/CU, independent blocks.
__global__ __launch_bounds__(256, 1) void xg_gemm(
    const unsigned short* __restrict__ xb,    // [T][64][1024] bf16
    const unsigned short* __restrict__ wih,   // [4096][1024] bf16
    const float* __restrict__ bsum,           // [4096] f32
    char* __restrict__ xg, int xg32)
{
  const int tid = threadIdx.x;
  const int wid = tid >> 6;
  const int lane = tid & 63;
  const int ln15 = lane & 15;
  const int quad = lane >> 4;
  const int bid = blockIdx.x;
  const int cb = (bid & 7) | ((bid >> 4) << 3);   // 0..127
  const int t0 = ((bid >> 3) & 1) * 256;          // t-half
  const int hc0 = cb * HPB;
  const int koff = wid * 256;                     // 4-way K split

  __shared__ float red[4][64][36];
  __shared__ __align__(16) short xstage[4][2][4096];  // [wave][buf][8KB]

  short8 bfrag[8][2];
#pragma unroll
  for (int nt = 0; nt < 2; ++nt) {
    int n = nt * 16 + ln15;
    int grow = (n >> 3) * 1024 + hc0 + (n & 7);
#pragma unroll
    for (int kc = 0; kc < 8; ++kc) {
      int k = koff + kc * 32 + quad * 8;
      bfrag[kc][nt] = load_frag(wih + grow * 1024 + k);
    }
  }

  const int eb = tid >> 2;
  const int erp = tid & 3;
  float bsv[4][2];
#pragma unroll
  for (int q = 0; q < 4; ++q)
#pragma unroll
    for (int rr = 0; rr < 2; ++rr)
      bsv[q][rr] = bsum[q * 1024 + hc0 + erp * 2 + rr];

  const unsigned xrow = (unsigned)(lane >> 3);
  const unsigned xlane = xrow * 2048u + (unsigned)wid * 512u +
                         (((unsigned)(lane & 7) ^ xrow) * 16u);
  const unsigned lsw = (unsigned)(ln15 & 7) << 4;
  const unsigned q16 = (unsigned)quad * 16u;

  f32x4 acc[4][2];

  auto stage_x = [&](int t, int ck, int buf) {
    short* lb = &xstage[wid][buf][0];
    const char* gt = (const char*)xb + (size_t)t * 131072u;
#pragma unroll
    for (int j = 0; j < 8; ++j) {
      unsigned off = xlane + (unsigned)j * 16384u + (unsigned)ck * 128u;
      __builtin_amdgcn_global_load_lds((gvoid*)(gt + off),
                                       (lvoid*)(lb + j * 512), 16, 0, 0);
    }
  };
  auto comp_x = [&](int ck, int buf) {
    const char* lb = (const char*)&xstage[wid][buf][0];
#pragma unroll
    for (int kl = 0; kl < 2; ++kl) {
      int kc = ck * 2 + kl;
#pragma unroll
      for (int m = 0; m < 4; ++m) {
        unsigned loff = (unsigned)m * 2048u + (unsigned)ln15 * 128u +
                        (((unsigned)kl * 64u + q16) ^ lsw);
        short8 a = *(const short8*)(lb + loff);
        acc[m][0] = __builtin_amdgcn_mfma_f32_16x16x32_bf16(
            a, bfrag[kc][0], acc[m][0], 0, 0, 0);
        acc[m][1] = __builtin_amdgcn_mfma_f32_16x16x32_bf16(
            a, bfrag[kc][1], acc[m][1], 0, 0, 0);
      }
    }
  };

  stage_x(t0, 0, 0);
  stage_x(t0, 1, 1);

#pragma unroll 1
  for (int ti = 0; ti < 256; ++ti) {
    const int t = t0 + ti;
#pragma unroll
    for (int m = 0; m < 4; ++m)
#pragma unroll
      for (int nt = 0; nt < 2; ++nt)
        acc[m][nt] = (f32x4){0.0f, 0.0f, 0.0f, 0.0f};

    asm volatile("s_waitcnt vmcnt(8)" ::: "memory");
    comp_x(0, 0);
    asm volatile("s_waitcnt lgkmcnt(0)" ::: "memory");
    stage_x(t, 2, 0);
    asm volatile("s_waitcnt vmcnt(8)" ::: "memory");
    comp_x(1, 1);
    asm volatile("s_waitcnt lgkmcnt(0)" ::: "memory");
    stage_x(t, 3, 1);
    asm volatile("s_waitcnt vmcnt(8)" ::: "memory");
    comp_x(2, 0);
    asm volatile("s_waitcnt vmcnt(0)" ::: "memory");
    comp_x(3, 1);

#pragma unroll
    for (int m = 0; m < 4; ++m)
#pragma unroll
      for (int nt = 0; nt < 2; ++nt)
#pragma unroll
        for (int p = 0; p < 4; ++p)
          red[wid][m * 16 + quad * 4 + p][nt * 16 + ln15] = acc[m][nt][p];

    asm volatile("s_waitcnt lgkmcnt(0)" ::: "memory");
    __builtin_amdgcn_s_barrier();

    size_t xoff = (((size_t)cb * 512 + (size_t)t) * 64 + (size_t)eb) * 32 +
                  (size_t)(erp * 2);
    float s[4][2];
#pragma unroll
    for (int rr = 0; rr < 2; ++rr) {
      int r = erp * 2 + rr;
#pragma unroll
      for (int q = 0; q < 4; ++q) {
        int col = q * 8 + r;
        s[q][rr] = red[0][eb][col] + red[1][eb][col] + red[2][eb][col] +
                   red[3][eb][col] + bsv[q][rr];
      }
    }
    if (xg32) {
      float* xp = (float*)xg + xoff;
#pragma unroll
      for (int q = 0; q < 4; ++q) {
        float2 v; v.x = s[q][0]; v.y = s[q][1];
        *(float2*)(xp + q * 8) = v;
      }
    } else {
      unsigned short* xp = (unsigned short*)xg + xoff;
#pragma unroll
      for (int q = 0; q < 4; ++q) {
        unsigned u = (unsigned)f2bf(s[q][0]) | ((unsigned)f2bf(s[q][1]) << 16);
        *(unsigned*)(xp + q * 8) = u;
      }
    }

    if (ti < 255) {
      stage_x(t + 1, 0, 0);
      stage_x(t + 1, 1, 1);
    }
    asm volatile("s_waitcnt lgkmcnt(0)" ::: "memory");
    __builtin_amdgcn_s_barrier();
  }
}

// ---- persistent LSTM recurrence ---------------------------------------
// h: 64-slab ring, slab t&63 = h(t), [128 cb][64 row][8 col] bf16 each.
// Writes: sc0sc1 write-through (MALL). Reads: L2-CACHED global_load_lds
// (16 same-XCD blocks share one fetch). Coherence: slab address reuse
// distance = 63 steps; agent acquire-fence every 32 steps guarantees >=1
// L2 invalidate between any read and that address's re-read.
__global__ __launch_bounds__(256, 1) void lstm_persist(
    const unsigned short* __restrict__ whh,   // [4096][1024] bf16
    const char* __restrict__ xg, int xg32,    // [128][512][64][32]
    unsigned short* __restrict__ hbuf,        // 64 x [128][64][8] bf16 ring
    unsigned int* __restrict__ barrier_mem,   // zeroed
    float* __restrict__ out)                  // [64][1024] f32
{
  const int tid = threadIdx.x;
  const int wid = tid >> 6;
  const int lane = tid & 63;
  const int ln15 = lane & 15;
  const int quad = lane >> 4;
  const int cb = blockIdx.x;
  const int hc0 = cb * HPB;
  const int koff = wid * 256;        // 4-way K split over W_hh

  unsigned int* epoch = barrier_mem;
  unsigned int* root = barrier_mem + 32;
  unsigned int* leaf = barrier_mem + 64 + (cb >> 4) * 32;

  __shared__ float red[4][64][36];
  __shared__ __align__(16) short hstage[4][2][4096];  // [wave][buf][8KB]
  __shared__ unsigned ready;

  short8 bfrag[8][2];
#pragma unroll
  for (int nt = 0; nt < 2; ++nt) {
    int n = nt * 16 + ln15;
    int grow = (n >> 3) * 1024 + hc0 + (n & 7);
#pragma unroll
    for (int kc = 0; kc < 8; ++kc) {
      int k = koff + kc * 32 + quad * 8;
      bfrag[kc][nt] = load_frag(whh + grow * 1024 + k);
    }
  }

  const int eb = tid >> 2;
  const int erp = tid & 3;
  const size_t xbase0 = (((size_t)cb * 512) * 64 + (size_t)eb) * 32 +
                        (size_t)(erp * 2);

  if (tid == 0) ready = 0u;
  __syncthreads();

  float cst[2] = {0.0f, 0.0f};
  f32x4 acc[4][2];

  auto stage = [&](const char* gsrc, int ck, int buf) {
    short* lb = &hstage[wid][buf][0];
    const char* gs = gsrc + wid * 32768 + ck * 8192 + (unsigned)lane * 16u;
#pragma unroll
    for (int j = 0; j < 8; ++j) {
      // aux=0: L2-cached. Safe: slab addresses are write-once within any
      // 63-step window and the periodic fence invalidates older lines.
      __builtin_amdgcn_global_load_lds((gvoid*)(gs + j * 1024),
                                       (lvoid*)(lb + j * 512),
                                       16, 0, 0);
    }
  };
  auto comp = [&](int ck, int buf) {
    const char* lb = (const char*)&hstage[wid][buf][0];
#pragma unroll
    for (int kl = 0; kl < 2; ++kl) {
      int kc = ck * 2 + kl;
#pragma unroll
      for (int m = 0; m < 4; ++m) {
        unsigned loff = (unsigned)(kl * 4 + quad) * 1024u +
                        (unsigned)(m * 16 + ln15) * 16u;
        short8 a = *(const short8*)(lb + loff);
        acc[m][0] = __builtin_amdgcn_mfma_f32_16x16x32_bf16(
            a, bfrag[kc][0], acc[m][0], 0, 0, 0);
        acc[m][1] = __builtin_amdgcn_mfma_f32_16x16x32_bf16(
            a, bfrag[kc][1], acc[m][1], 0, 0, 0);
      }
    }
  };

#pragma unroll 1
  for (int t = 0; t < TT; ++t) {
    // xg slice load: independent of the epoch -> issue BEFORE the poll.
    float xgv[4][2];
    if (xg32) {
      const float* xp = (const float*)xg + xbase0 + (size_t)t * 2048u;
#pragma unroll
      for (int q = 0; q < 4; ++q) {
        float2 v = *(const float2*)(xp + q * 8);
        xgv[q][0] = v.x; xgv[q][1] = v.y;
      }
    } else {
      const unsigned short* xp =
          (const unsigned short*)xg + xbase0 + (size_t)t * 2048u;
#pragma unroll
      for (int q = 0; q < 4; ++q) {
        unsigned u = *(const unsigned*)(xp + q * 8);
        xgv[q][0] = __builtin_bit_cast(float, u << 16);
        xgv[q][1] = __builtin_bit_cast(float, u & 0xffff0000u);
      }
    }

#pragma unroll
    for (int m = 0; m < 4; ++m)
#pragma unroll
      for (int nt = 0; nt < 2; ++nt)
        acc[m][nt] = (f32x4){0.0f, 0.0f, 0.0f, 0.0f};

    if (t) {
      // poll: wave0 lane0 on the MALL epoch word, others on LDS relay
      if (wid == 0) {
        if (lane == 0) {
          while (__hip_atomic_load(epoch, __ATOMIC_RELAXED,
                                   __HIP_MEMORY_SCOPE_AGENT) < (unsigned)t)
            __builtin_amdgcn_s_sleep(1);
          __hip_atomic_store(&ready, (unsigned)t, __ATOMIC_RELAXED,
                             __HIP_MEMORY_SCOPE_WORKGROUP);
        }
      } else {
        while (__hip_atomic_load(&ready, __ATOMIC_RELAXED,
                                 __HIP_MEMORY_SCOPE_WORKGROUP) < (unsigned)t)
          __builtin_amdgcn_s_sleep(1);
      }

      // periodic acquire: one L2 invalidate per 32 steps covers slab
      // address reuse (distance 63). NOT per-step (R4's mistake).
      if ((t & 31) == 0)
        __builtin_amdgcn_fence(__ATOMIC_ACQUIRE, "agent");

      const char* gsrc = (const char*)(hbuf + (size_t)(t & 63) * 65536u);
      stage(gsrc, 0, 0);
      stage(gsrc, 1, 1);
      asm volatile("s_waitcnt vmcnt(8)" ::: "memory");
      comp(0, 0);
      asm volatile("s_waitcnt lgkmcnt(0)" ::: "memory");
      stage(gsrc, 2, 0);
      asm volatile("s_waitcnt vmcnt(8)" ::: "memory");
      comp(1, 1);
      asm volatile("s_waitcnt lgkmcnt(0)" ::: "memory");
      stage(gsrc, 3, 1);
      asm volatile("s_waitcnt vmcnt(8)" ::: "memory");
      comp(2, 0);
      asm volatile("s_waitcnt vmcnt(0)" ::: "memory");
      comp(3, 1);
    }
    // t==0: h0 = 0 -> gates are xg only; acc stays zero.

#pragma unroll
    for (int m = 0; m < 4; ++m)
#pragma unroll
      for (int nt = 0; nt < 2; ++nt)
#pragma unroll
        for (int p = 0; p < 4; ++p)
          red[wid][m * 16 + quad * 4 + p][nt * 16 + ln15] = acc[m][nt][p];

    asm volatile("s_waitcnt lgkmcnt(0)" ::: "memory");
    __builtin_amdgcn_s_barrier();   // (#1) raw

    float hv[2];
#pragma unroll
    for (int rr = 0; rr < 2; ++rr) {
      int r = erp * 2 + rr;
      float g[4];
#pragma unroll
      for (int q = 0; q < 4; ++q) {
        int col = q * 8 + r;
        g[q] = red[0][eb][col] + red[1][eb][col] + red[2][eb][col] +
               red[3][eb][col] + xgv[q][rr];
      }
      float ig = sigm(g[0]);
      float fg = sigm(g[1]);
      float gg = tanh_f(g[2]);
      float og = sigm(g[3]);
      float c = fg * cst[rr] + ig * gg;
      cst[rr] = c;
      hv[rr] = og * tanh_f(c);
    }
    unsigned hpack = (unsigned)f2bf(hv[0]) | ((unsigned)f2bf(hv[1]) << 16);
    // write h(t+1) into ring slab (t+1)&63: sc0sc1 write-through to MALL
    __hip_atomic_store(
        (unsigned*)(hbuf + (size_t)((t + 1) & 63) * 65536u + cb * 512 +
                    eb * 8 + erp * 2),
        hpack, __ATOMIC_RELAXED, __HIP_MEMORY_SCOPE_AGENT);

    if (t == TT - 1) {
      float2 o2; o2.x = hv[0]; o2.y = hv[1];
      *(float2*)(out + eb * HHH + hc0 + erp * 2) = o2;
    }

    __syncthreads();   // (#2) vmcnt(0): h stores MALL-visible

    if (t < TT - 1 && tid == 0) {
      unsigned old = atomicAdd(leaf, 1u);
      if (old == (unsigned)t * 16u + 15u) {
        unsigned old2 = atomicAdd(root, 1u);
        if (old2 == (unsigned)t * 8u + 7u)
          atomicExch(epoch, (unsigned)(t + 1));
      }
    }
  }
}

// ---- launcher ----------------------------------------------------------
extern "C" void kernel_launch(void* const* d_in, const int* in_sizes, int n_in,
                              void* d_out, int out_size, void* d_ws,
                              size_t ws_size, hipStream_t stream) {
  (void)in_sizes; (void)n_in; (void)out_size;
  const float* x   = (const float*)d_in[0];
  const float* wih = (const float*)d_in[1];
  const float* whh = (const float*)d_in[2];
  const float* bih = (const float*)d_in[3];
  const float* bhh = (const float*)d_in[4];

  char* ws = (char*)d_ws;
  // workspace layout (bytes):
  //   [0, 4KiB)          barrier counters
  //   [1MiB, 9MiB)       h ring: 64 slabs x 128KiB
  //   [9MiB, 17MiB)      W_ih bf16
  //   [17MiB, 25MiB)     W_hh bf16
  //   [25MiB, +16KiB)    bias sum f32
  //   [26MiB, 90MiB)     x bf16
  //   [96MiB, ...)       xg: f32 512MiB if ws fits, else bf16 256MiB
  unsigned int*   bar  = (unsigned int*)(ws);
  unsigned short* hb   = (unsigned short*)(ws + (1ull << 20));
  unsigned short* wihb = (unsigned short*)(ws + (9ull << 20));
  unsigned short* whhb = (unsigned short*)(ws + (17ull << 20));
  float*          bs   = (float*)(ws + (25ull << 20));
  unsigned short* xb   = (unsigned short*)(ws + (26ull << 20));
  char*           xg   = ws + (96ull << 20);
  int xg32 = (ws_size >= (640ull << 20)) ? 1 : 0;

  hipMemsetAsync(ws, 0, 4096, stream);

  cvt_bf16<<<2048, 256, 0, stream>>>(x, xb, (TT * BB * II) / 4);
  cvt_bf16<<<1024, 256, 0, stream>>>(wih, wihb, (G4 * II) / 4);
  cvt_bf16<<<1024, 256, 0, stream>>>(whh, whhb, (G4 * HHH) / 4);
  bias_sum<<<16, 256, 0, stream>>>(bih, bhh, bs);

  xg_gemm<<<256, 256, 0, stream>>>(xb, wihb, bs, xg, xg32);
  lstm_persist<<<NBLK, 256, 0, stream>>>(whhb, xg, xg32, hb, bar,
                                         (float*)d_out);
}